// Round 1
// baseline (1815.267 us; speedup 1.0000x reference)
//
#include <hip/hip_runtime.h>
#include <math.h>

// ---------------------------------------------------------------------------
// SVDNet: conv stack -> fc trunk -> {s head + sort, u/v heads -> CholeskyQR}
// All fp32. CholeskyQR (G = X^H X + eps*I, G = R^H R, Q = X R^-1) replaces the
// reference's sequential modified Gram-Schmidt (identical in exact arithmetic).
// R2: k_chol rewritten LDS-resident (packed upper triangle, exactly 64 KiB).
// ---------------------------------------------------------------------------

__device__ __forceinline__ float wave_reduce_sum(float v) {
#pragma unroll
  for (int off = 32; off > 0; off >>= 1) v += __shfl_down(v, off, 64);
  return v;
}

__global__ void k_zero(float* __restrict__ p, int n) {
  int i = blockIdx.x * 256 + threadIdx.x;
  if (i < n) p[i] = 0.f;
}

// ---------------- conv1: 2 -> 32, 3x3 pad1, relu, 512x512, CHW out ----------
__global__ __launch_bounds__(256) void k_conv1(const float* __restrict__ x,
                                               const float* __restrict__ w,
                                               const float* __restrict__ b,
                                               float* __restrict__ h1) {
  __shared__ float tile[2][18][18];
  const int tx = threadIdx.x & 15, ty = threadIdx.x >> 4;
  const int bx = blockIdx.x * 16, by = blockIdx.y * 16;
  for (int idx = threadIdx.x; idx < 2 * 18 * 18; idx += 256) {
    int c = idx / 324, r = idx - c * 324;
    int yy = r / 18, xx = r - yy * 18;
    int gy = by + yy - 1, gx = bx + xx - 1;
    float v = 0.f;
    if ((unsigned)gy < 512u && (unsigned)gx < 512u) v = x[(gy * 512 + gx) * 2 + c];
    tile[c][yy][xx] = v;
  }
  __syncthreads();
  float in[2][3][3];
#pragma unroll
  for (int c = 0; c < 2; ++c)
#pragma unroll
    for (int ky = 0; ky < 3; ++ky)
#pragma unroll
      for (int kx = 0; kx < 3; ++kx) in[c][ky][kx] = tile[c][ty + ky][tx + kx];
  const int gy = by + ty, gx = bx + tx;
#pragma unroll 4
  for (int oc = 0; oc < 32; ++oc) {
    float acc = b[oc];
#pragma unroll
    for (int c = 0; c < 2; ++c)
#pragma unroll
      for (int ky = 0; ky < 3; ++ky)
#pragma unroll
        for (int kx = 0; kx < 3; ++kx)
          acc = fmaf(w[((oc * 2 + c) * 3 + ky) * 3 + kx], in[c][ky][kx], acc);
    h1[oc * 262144 + gy * 512 + gx] = fmaxf(acc, 0.f);
  }
}

// -------- conv2: 32 -> 64, 3x3 pad1, relu, then 2x2 maxpool -> (64,256,256) --
__global__ __launch_bounds__(256) void k_conv2pool(const float* __restrict__ h1,
                                                   const float* __restrict__ w,
                                                   const float* __restrict__ b,
                                                   float* __restrict__ pooled) {
  __shared__ float tile[8][34][34];  // 37 KB
  const int tx = threadIdx.x & 15, ty = threadIdx.x >> 4;
  const int px0 = blockIdx.x * 16, py0 = blockIdx.y * 16;
  const int ocg = blockIdx.z;  // 8 output channels per block
  const int cx0 = px0 * 2 - 1, cy0 = py0 * 2 - 1;
  float acc[2][2][8];
#pragma unroll
  for (int a = 0; a < 2; ++a)
#pragma unroll
    for (int c = 0; c < 2; ++c)
#pragma unroll
      for (int o = 0; o < 8; ++o) acc[a][c][o] = 0.f;
  for (int icc = 0; icc < 4; ++icc) {
    __syncthreads();
    for (int idx = threadIdx.x; idx < 8 * 34 * 34; idx += 256) {
      int ic = idx / 1156, r = idx - ic * 1156;
      int yy = r / 34, xx = r - yy * 34;
      int gy = cy0 + yy, gx = cx0 + xx;
      float v = 0.f;
      if ((unsigned)gy < 512u && (unsigned)gx < 512u)
        v = h1[(icc * 8 + ic) * 262144 + gy * 512 + gx];
      tile[ic][yy][xx] = v;
    }
    __syncthreads();
#pragma unroll
    for (int ic = 0; ic < 8; ++ic) {
      float reg[4][4];
#pragma unroll
      for (int r = 0; r < 4; ++r)
#pragma unroll
        for (int c = 0; c < 4; ++c) reg[r][c] = tile[ic][2 * ty + r][2 * tx + c];
#pragma unroll
      for (int oc = 0; oc < 8; ++oc) {
        const float* wp = w + (((ocg * 8 + oc) * 32 + icc * 8 + ic) * 9);
#pragma unroll
        for (int ky = 0; ky < 3; ++ky)
#pragma unroll
          for (int kx = 0; kx < 3; ++kx) {
            float wv = wp[ky * 3 + kx];  // uniform -> scalar load
#pragma unroll
            for (int dy = 0; dy < 2; ++dy)
#pragma unroll
              for (int dx = 0; dx < 2; ++dx)
                acc[dy][dx][oc] = fmaf(wv, reg[dy + ky][dx + kx], acc[dy][dx][oc]);
          }
      }
    }
  }
  const int py = py0 + ty, px = px0 + tx;
#pragma unroll
  for (int oc = 0; oc < 8; ++oc) {
    float bb = b[ocg * 8 + oc];
    float v00 = fmaxf(acc[0][0][oc] + bb, 0.f);
    float v01 = fmaxf(acc[0][1][oc] + bb, 0.f);
    float v10 = fmaxf(acc[1][0][oc] + bb, 0.f);
    float v11 = fmaxf(acc[1][1][oc] + bb, 0.f);
    pooled[(ocg * 8 + oc) * 65536 + py * 256 + px] = fmaxf(fmaxf(v00, v01), fmaxf(v10, v11));
  }
}

// -------- conv3: 64 -> 128, 3x3 pad1, relu, fused global mean (partials) ----
__global__ __launch_bounds__(256) void k_conv3mean(const float* __restrict__ pooled,
                                                   const float* __restrict__ w,
                                                   const float* __restrict__ b,
                                                   float* __restrict__ feat_part) {
  __shared__ float tile[8][18][18];
  __shared__ float red[32];
  const int tx = threadIdx.x & 15, ty = threadIdx.x >> 4;
  const int x0 = blockIdx.x * 16, y0 = blockIdx.y * 16;
  const int ocg = blockIdx.z;  // 8 output channels per block
  float acc[8];
#pragma unroll
  for (int o = 0; o < 8; ++o) acc[o] = 0.f;
  for (int icc = 0; icc < 8; ++icc) {
    __syncthreads();
    for (int idx = threadIdx.x; idx < 8 * 18 * 18; idx += 256) {
      int ic = idx / 324, r = idx - ic * 324;
      int yy = r / 18, xx = r - yy * 18;
      int gy = y0 + yy - 1, gx = x0 + xx - 1;
      float v = 0.f;
      if ((unsigned)gy < 256u && (unsigned)gx < 256u)
        v = pooled[(icc * 8 + ic) * 65536 + gy * 256 + gx];
      tile[ic][yy][xx] = v;
    }
    __syncthreads();
#pragma unroll
    for (int ic = 0; ic < 8; ++ic) {
      float reg[3][3];
#pragma unroll
      for (int r = 0; r < 3; ++r)
#pragma unroll
        for (int c = 0; c < 3; ++c) reg[r][c] = tile[ic][ty + r][tx + c];
#pragma unroll
      for (int oc = 0; oc < 8; ++oc) {
        const float* wp = w + (((ocg * 8 + oc) * 64 + icc * 8 + ic) * 9);
#pragma unroll
        for (int ky = 0; ky < 3; ++ky)
#pragma unroll
          for (int kx = 0; kx < 3; ++kx)
            acc[oc] = fmaf(wp[ky * 3 + kx], reg[ky][kx], acc[oc]);
      }
    }
  }
  const int lane = threadIdx.x & 63, wid = threadIdx.x >> 6;
#pragma unroll
  for (int oc = 0; oc < 8; ++oc) {
    float v = fmaxf(acc[oc] + b[ocg * 8 + oc], 0.f);
    v = wave_reduce_sum(v);
    if (lane == 0) red[wid * 8 + oc] = v;
  }
  __syncthreads();
  if (threadIdx.x < 8) {
    float s = red[threadIdx.x] + red[8 + threadIdx.x] + red[16 + threadIdx.x] + red[24 + threadIdx.x];
    int bucket = (blockIdx.y * 16 + blockIdx.x) & 31;
    atomicAdd(&feat_part[bucket * 128 + ocg * 8 + (int)threadIdx.x], s);
  }
}

__global__ void k_featreduce(const float* __restrict__ feat_part, float* __restrict__ feat) {
  int j = threadIdx.x;  // 128 threads
  float s = 0.f;
  for (int bkt = 0; bkt < 32; ++bkt) s += feat_part[bkt * 128 + j];
  feat[j] = s * (1.f / 65536.f);
}

// ---------------- generic small matvec: y = relu(W x + b), wave per row ------
__global__ __launch_bounds__(256) void k_matvec_small(const float* __restrict__ W,
                                                      const float* __restrict__ b,
                                                      const float* __restrict__ x,
                                                      float* __restrict__ y,
                                                      int nrows, int ncols) {
  const int wid = threadIdx.x >> 6, lane = threadIdx.x & 63;
  const int row = blockIdx.x * 4 + wid;
  if (row >= nrows) return;
  const float* wr = W + (size_t)row * ncols;
  float p = 0.f;
  for (int c = lane; c < ncols; c += 64) p = fmaf(wr[c], x[c], p);
  p = wave_reduce_sum(p);
  if (lane == 0) y[row] = fmaxf(p + b[row], 0.f);
}

// ------- big head matvecs: u (131072x512), v (131072x512), s2 (128x256) -----
__global__ __launch_bounds__(256) void k_heads_big(
    const float* __restrict__ uw2, const float* __restrict__ ub2,
    const float* __restrict__ vw2, const float* __restrict__ vb2,
    const float* __restrict__ sw2, const float* __restrict__ sb2,
    const float* __restrict__ u1, const float* __restrict__ v1,
    const float* __restrict__ s1, float* __restrict__ u_buf,
    float* __restrict__ v_buf, float* __restrict__ s_raw) {
  const int wid = threadIdx.x >> 6, lane = threadIdx.x & 63;
  const int row = blockIdx.x * 4 + wid;
  if (row < 262144) {
    int r = row & 131071;
    const float* W = (row < 131072) ? uw2 : vw2;
    const float* xv = (row < 131072) ? u1 : v1;
    const float4* wr = (const float4*)(W + (size_t)r * 512);
    const float4* xp = (const float4*)xv;
    float4 a0 = wr[lane], a1 = wr[lane + 64];
    float4 b0 = xp[lane], b1 = xp[lane + 64];
    float p = a0.x * b0.x;
    p = fmaf(a0.y, b0.y, p); p = fmaf(a0.z, b0.z, p); p = fmaf(a0.w, b0.w, p);
    p = fmaf(a1.x, b1.x, p); p = fmaf(a1.y, b1.y, p);
    p = fmaf(a1.z, b1.z, p); p = fmaf(a1.w, b1.w, p);
    p = wave_reduce_sum(p);
    if (lane == 0) {
      if (row < 131072) u_buf[r] = p + ub2[r];
      else v_buf[r] = p + vb2[r];
    }
  } else {
    int r = row - 262144;  // 0..127
    if (r < 128) {
      const float* wr = sw2 + (size_t)r * 256;
      float p = 0.f;
      for (int c = lane; c < 256; c += 64) p = fmaf(wr[c], s1[c], p);
      p = wave_reduce_sum(p);
      if (lane == 0) {
        float z = p + sb2[r];
        s_raw[r] = (z > 20.f) ? z : log1pf(expf(z));
      }
    }
  }
}

// ---------------- sort s descending (stable, matches sort+reverse) ----------
__global__ void k_sort(const float* __restrict__ s_raw, float* __restrict__ out) {
  __shared__ float sv[128];
  const int t = threadIdx.x;  // 128 threads
  float v = s_raw[t];
  sv[t] = v;
  __syncthreads();
  int rank = 0;
  for (int k = 0; k < 128; ++k) {
    float o = sv[k];
    rank += (o > v) || (o == v && k > t);
  }
  out[rank] = v;
}

// ----- G = X^H X (+eps I), upper triangle; strict lower zero-filled ---------
__global__ __launch_bounds__(256) void k_gram(const float* __restrict__ Xu,
                                              const float* __restrict__ Xv,
                                              float2* __restrict__ Gu,
                                              float2* __restrict__ Gv) {
  const int mat = blockIdx.z;
  const float* X = mat ? Xv : Xu;
  float2* G = mat ? Gv : Gu;
  const int bi = blockIdx.y, bj = blockIdx.x;
  const int ti = threadIdx.x >> 4, tj = threadIdx.x & 15;
  const int i = bi * 16 + ti, j = bj * 16 + tj;
  if (bi > bj) {  // uniform across block
    G[i * 128 + j] = make_float2(0.f, 0.f);
    return;
  }
  __shared__ float2 A[32][16];
  __shared__ float2 B[32][16];
  float are = 0.f, aim = 0.f;
  for (int m0 = 0; m0 < 512; m0 += 32) {
    __syncthreads();
    for (int t = threadIdx.x; t < 512; t += 256) {
      int ml = t >> 4, c = t & 15;
      A[ml][c] = *(const float2*)(X + (m0 + ml) * 256 + (bi * 16 + c) * 2);
      B[ml][c] = *(const float2*)(X + (m0 + ml) * 256 + (bj * 16 + c) * 2);
    }
    __syncthreads();
#pragma unroll
    for (int ml = 0; ml < 32; ++ml) {
      float2 a = A[ml][ti], bb = B[ml][tj];
      are = fmaf(a.x, bb.x, fmaf(a.y, bb.y, are));   // conj(a)*b real
      aim = fmaf(a.x, bb.y, fmaf(-a.y, bb.x, aim));  // conj(a)*b imag
    }
  }
  if (i > j) G[i * 128 + j] = make_float2(0.f, 0.f);
  else if (i == j) G[i * 128 + j] = make_float2(are + 1e-8f, 0.f);
  else G[i * 128 + j] = make_float2(are, aim);
}

// ------------- in-place Hermitian Cholesky (upper): G -> R, R^H R = G -------
// LDS-resident: packed strict-upper triangle (8128 float2) + diag (128 float)
// = exactly 65536 B. rof(i) = i*(255-i)/2 row offsets computed inline.
__device__ __forceinline__ int rof(int i) { return (i * (255 - i)) >> 1; }
__device__ __forceinline__ int row_of(int idx) {
  int i = (int)(127.5f - sqrtf(16256.25f - 2.0f * (float)idx));
  if (i < 0) i = 0;
  if (i > 126) i = 126;
  while (rof(i + 1) <= idx) ++i;
  while (rof(i) > idx) --i;
  return i;
}

__global__ __launch_bounds__(256) void k_chol(float2* __restrict__ Gu, float2* __restrict__ Gv) {
  float2* G = blockIdx.x ? Gv : Gu;
  __shared__ float smem[16384];  // 64 KiB exactly
  float2* U = (float2*)smem;     // [0..8128) packed strict-upper
  float* diag = smem + 16256;    // [16256..16384)
  const int tid = threadIdx.x;
  // ---- load from global ----
  for (int j = tid; j < 128; j += 256) diag[j] = G[j * 128 + j].x;  // has +1e-8
  for (int idx = tid; idx < 8128; idx += 256) {
    int i = row_of(idx);
    int k = i + 1 + (idx - rof(i));
    U[idx] = G[i * 128 + k];
  }
  __syncthreads();
  // ---- right-looking factorization ----
  const int g = tid >> 6, lane = tid & 63;
  for (int j = 0; j < 128; ++j) {
    if (tid == 0) diag[j] = sqrtf(diag[j]);
    __syncthreads();
    const float invd = 1.f / diag[j];
    const int base_j = rof(j) - j - 1;
    for (int k = j + 1 + tid; k < 128; k += 256) {
      float2 v = U[base_j + k];
      v.x *= invd; v.y *= invd;
      U[base_j + k] = v;
    }
    __syncthreads();
    for (int i = j + 1 + g; i < 128; i += 4) {
      float2 rji = U[base_j + i];
      int base_i = rof(i) - i - 1;
      for (int k = i + lane; k < 128; k += 64) {
        float2 rjk = U[base_j + k];
        if (k == i) {
          diag[i] -= rji.x * rji.x + rji.y * rji.y;
        } else {
          float2 gg = U[base_i + k];
          gg.x -= rji.x * rjk.x + rji.y * rjk.y;   // conj(rji)*rjk
          gg.y -= rji.x * rjk.y - rji.y * rjk.x;
          U[base_i + k] = gg;
        }
      }
    }
    __syncthreads();
  }
  // ---- store back (lower triangle already zero from k_gram) ----
  for (int j = tid; j < 128; j += 256) G[j * 128 + j] = make_float2(diag[j], 0.f);
  for (int idx = tid; idx < 8128; idx += 256) {
    int i = row_of(idx);
    int k = i + 1 + (idx - rof(i));
    G[i * 128 + k] = U[idx];
  }
}

// --------- Q = X R^-1, wave-per-row forward substitution, write d_out -------
__global__ __launch_bounds__(256) void k_solve(const float* __restrict__ Xu,
                                               const float* __restrict__ Xv,
                                               const float2* __restrict__ Gu,
                                               const float2* __restrict__ Gv,
                                               float* __restrict__ out) {
  const int wid = threadIdx.x >> 6, lane = threadIdx.x & 63;
  const int gw = blockIdx.x * 4 + wid;  // 0..1023
  const int mat = gw >> 9, m = gw & 511;
  const float* X = mat ? Xv : Xu;
  const float* R = (const float*)(mat ? Gv : Gu);
  float* o = out + (mat ? 131200 : 0);
  float4 xv = *(const float4*)(X + m * 256 + lane * 4);  // cols 2l (x,y), 2l+1 (z,w)
  float S0re = 0.f, S0im = 0.f, S1re = 0.f, S1im = 0.f;
  float q0re = 0.f, q0im = 0.f, q1re = 0.f, q1im = 0.f;
  float4 rp = *(const float4*)(R + lane * 4);  // row 0
  for (int i = 0; i < 128; ++i) {
    float4 rp_next;
    if (i < 127) rp_next = *(const float4*)(R + (i + 1) * 256 + lane * 4);
    const bool odd = (i & 1);
    float d = odd ? rp.z : rp.x;  // true diagonal only in owner lane (i>>1)
    float xs_re = odd ? xv.z : xv.x, xs_im = odd ? xv.w : xv.y;
    float Ss_re = odd ? S1re : S0re, Ss_im = odd ? S1im : S0im;
    float invd = 1.f / d;  // garbage in non-owner lanes, discarded by shuffle
    float qre = (xs_re - Ss_re) * invd;
    float qim = (xs_im - Ss_im) * invd;
    qre = __shfl(qre, i >> 1, 64);
    qim = __shfl(qim, i >> 1, 64);
    if (lane == (i >> 1)) {
      if (odd) { q1re = qre; q1im = qim; }
      else     { q0re = qre; q0im = qim; }
    }
    // S_j += q_i * R[i][j]  (R lower triangle is zero -> harmless for j <= i)
    S0re = fmaf(qre, rp.x, fmaf(-qim, rp.y, S0re));
    S0im = fmaf(qre, rp.y, fmaf(qim, rp.x, S0im));
    S1re = fmaf(qre, rp.z, fmaf(-qim, rp.w, S1re));
    S1im = fmaf(qre, rp.w, fmaf(qim, rp.z, S1im));
    rp = rp_next;
  }
  *(float4*)(o + m * 256 + lane * 4) = make_float4(q0re, q0im, q1re, q1im);
}

// ---------------------------------------------------------------------------
extern "C" void kernel_launch(void* const* d_in, const int* in_sizes, int n_in,
                              void* d_out, int out_size, void* d_ws, size_t ws_size,
                              hipStream_t stream) {
  const float* x   = (const float*)d_in[0];
  const float* cw1 = (const float*)d_in[1];  const float* cb1 = (const float*)d_in[2];
  const float* cw2 = (const float*)d_in[3];  const float* cb2 = (const float*)d_in[4];
  const float* cw3 = (const float*)d_in[5];  const float* cb3 = (const float*)d_in[6];
  const float* fw1 = (const float*)d_in[7];  const float* fb1 = (const float*)d_in[8];
  const float* fw2 = (const float*)d_in[9];  const float* fb2 = (const float*)d_in[10];
  const float* sw1 = (const float*)d_in[11]; const float* sb1 = (const float*)d_in[12];
  const float* sw2 = (const float*)d_in[13]; const float* sb2 = (const float*)d_in[14];
  const float* uw1 = (const float*)d_in[15]; const float* ub1 = (const float*)d_in[16];
  const float* uw2 = (const float*)d_in[17]; const float* ub2 = (const float*)d_in[18];
  const float* vw1 = (const float*)d_in[19]; const float* vb1 = (const float*)d_in[20];
  const float* vw2 = (const float*)d_in[21]; const float* vb2 = (const float*)d_in[22];

  float* ws = (float*)d_ws;
  float* h1        = ws;                    // 8388608
  float* pooled    = h1 + 8388608;          // 4194304
  float* feat_part = pooled + 4194304;      // 4096
  float* feat      = feat_part + 4096;      // 128
  float* y1        = feat + 128;            // 256
  float* f         = y1 + 256;              // 512
  float* s1        = f + 512;               // 256
  float* u1        = s1 + 256;              // 512
  float* v1        = u1 + 512;              // 512
  float* s_raw     = v1 + 512;              // 128
  float* u_buf     = s_raw + 128;           // 131072
  float* v_buf     = u_buf + 131072;        // 131072
  float2* Gu       = (float2*)(v_buf + 131072);  // 16384 float2
  float2* Gv       = Gu + 16384;                 // 16384 float2

  float* outp = (float*)d_out;  // [Qu 131072 | s 128 | Qv 131072]

  k_zero<<<16, 256, 0, stream>>>(feat_part, 4096);
  k_conv1<<<dim3(32, 32), 256, 0, stream>>>(x, cw1, cb1, h1);
  k_conv2pool<<<dim3(16, 16, 8), 256, 0, stream>>>(h1, cw2, cb2, pooled);
  k_conv3mean<<<dim3(16, 16, 16), 256, 0, stream>>>(pooled, cw3, cb3, feat_part);
  k_featreduce<<<1, 128, 0, stream>>>(feat_part, feat);
  k_matvec_small<<<64, 256, 0, stream>>>(fw1, fb1, feat, y1, 256, 128);
  k_matvec_small<<<128, 256, 0, stream>>>(fw2, fb2, y1, f, 512, 256);
  k_matvec_small<<<64, 256, 0, stream>>>(sw1, sb1, f, s1, 256, 512);
  k_matvec_small<<<128, 256, 0, stream>>>(uw1, ub1, f, u1, 512, 512);
  k_matvec_small<<<128, 256, 0, stream>>>(vw1, vb1, f, v1, 512, 512);
  k_heads_big<<<65568, 256, 0, stream>>>(uw2, ub2, vw2, vb2, sw2, sb2,
                                         u1, v1, s1, u_buf, v_buf, s_raw);
  k_sort<<<1, 128, 0, stream>>>(s_raw, outp + 131072);
  k_gram<<<dim3(8, 8, 2), 256, 0, stream>>>(u_buf, v_buf, Gu, Gv);
  k_chol<<<2, 256, 0, stream>>>(Gu, Gv);
  k_solve<<<256, 256, 0, stream>>>(u_buf, v_buf, Gu, Gv, outp);
}

// Round 2
// 1436.133 us; speedup vs baseline: 1.2640x; 1.2640x over previous
//
#include <hip/hip_runtime.h>
#include <math.h>

// ---------------------------------------------------------------------------
// SVDNet: conv stack -> fc trunk -> {s head + sort, u/v heads -> CholeskyQR}
// All fp32. CholeskyQR (G = X^H X + eps*I, G = R^H R, Q = X R^-1) replaces the
// reference's sequential modified Gram-Schmidt (identical in exact arithmetic).
// R2: k_chol LDS-resident (packed upper triangle, 64 KiB).
// R3: k_chol rewritten as deferred-normalization (LDL-style) factorization:
//     1 barrier/column (was 3 + serial sqrt), batched alias-free LDS reads
//     (read-phase / compute-phase / write-phase, fully unrolled, 1024 thr).
//     Was 596 us (latency-serial i-loop: compiler waitcnt between aliasing
//     LDS RMW iterations); predicted ~40-60 us.
// ---------------------------------------------------------------------------

__device__ __forceinline__ float wave_reduce_sum(float v) {
#pragma unroll
  for (int off = 32; off > 0; off >>= 1) v += __shfl_down(v, off, 64);
  return v;
}

__global__ void k_zero(float* __restrict__ p, int n) {
  int i = blockIdx.x * 256 + threadIdx.x;
  if (i < n) p[i] = 0.f;
}

// ---------------- conv1: 2 -> 32, 3x3 pad1, relu, 512x512, CHW out ----------
__global__ __launch_bounds__(256) void k_conv1(const float* __restrict__ x,
                                               const float* __restrict__ w,
                                               const float* __restrict__ b,
                                               float* __restrict__ h1) {
  __shared__ float tile[2][18][18];
  const int tx = threadIdx.x & 15, ty = threadIdx.x >> 4;
  const int bx = blockIdx.x * 16, by = blockIdx.y * 16;
  for (int idx = threadIdx.x; idx < 2 * 18 * 18; idx += 256) {
    int c = idx / 324, r = idx - c * 324;
    int yy = r / 18, xx = r - yy * 18;
    int gy = by + yy - 1, gx = bx + xx - 1;
    float v = 0.f;
    if ((unsigned)gy < 512u && (unsigned)gx < 512u) v = x[(gy * 512 + gx) * 2 + c];
    tile[c][yy][xx] = v;
  }
  __syncthreads();
  float in[2][3][3];
#pragma unroll
  for (int c = 0; c < 2; ++c)
#pragma unroll
    for (int ky = 0; ky < 3; ++ky)
#pragma unroll
      for (int kx = 0; kx < 3; ++kx) in[c][ky][kx] = tile[c][ty + ky][tx + kx];
  const int gy = by + ty, gx = bx + tx;
#pragma unroll 4
  for (int oc = 0; oc < 32; ++oc) {
    float acc = b[oc];
#pragma unroll
    for (int c = 0; c < 2; ++c)
#pragma unroll
      for (int ky = 0; ky < 3; ++ky)
#pragma unroll
        for (int kx = 0; kx < 3; ++kx)
          acc = fmaf(w[((oc * 2 + c) * 3 + ky) * 3 + kx], in[c][ky][kx], acc);
    h1[oc * 262144 + gy * 512 + gx] = fmaxf(acc, 0.f);
  }
}

// -------- conv2: 32 -> 64, 3x3 pad1, relu, then 2x2 maxpool -> (64,256,256) --
__global__ __launch_bounds__(256) void k_conv2pool(const float* __restrict__ h1,
                                                   const float* __restrict__ w,
                                                   const float* __restrict__ b,
                                                   float* __restrict__ pooled) {
  __shared__ float tile[8][34][34];  // 37 KB
  const int tx = threadIdx.x & 15, ty = threadIdx.x >> 4;
  const int px0 = blockIdx.x * 16, py0 = blockIdx.y * 16;
  const int ocg = blockIdx.z;  // 8 output channels per block
  const int cx0 = px0 * 2 - 1, cy0 = py0 * 2 - 1;
  float acc[2][2][8];
#pragma unroll
  for (int a = 0; a < 2; ++a)
#pragma unroll
    for (int c = 0; c < 2; ++c)
#pragma unroll
      for (int o = 0; o < 8; ++o) acc[a][c][o] = 0.f;
  for (int icc = 0; icc < 4; ++icc) {
    __syncthreads();
    for (int idx = threadIdx.x; idx < 8 * 34 * 34; idx += 256) {
      int ic = idx / 1156, r = idx - ic * 1156;
      int yy = r / 34, xx = r - yy * 34;
      int gy = cy0 + yy, gx = cx0 + xx;
      float v = 0.f;
      if ((unsigned)gy < 512u && (unsigned)gx < 512u)
        v = h1[(icc * 8 + ic) * 262144 + gy * 512 + gx];
      tile[ic][yy][xx] = v;
    }
    __syncthreads();
#pragma unroll
    for (int ic = 0; ic < 8; ++ic) {
      float reg[4][4];
#pragma unroll
      for (int r = 0; r < 4; ++r)
#pragma unroll
        for (int c = 0; c < 4; ++c) reg[r][c] = tile[ic][2 * ty + r][2 * tx + c];
#pragma unroll
      for (int oc = 0; oc < 8; ++oc) {
        const float* wp = w + (((ocg * 8 + oc) * 32 + icc * 8 + ic) * 9);
#pragma unroll
        for (int ky = 0; ky < 3; ++ky)
#pragma unroll
          for (int kx = 0; kx < 3; ++kx) {
            float wv = wp[ky * 3 + kx];  // uniform -> scalar load
#pragma unroll
            for (int dy = 0; dy < 2; ++dy)
#pragma unroll
              for (int dx = 0; dx < 2; ++dx)
                acc[dy][dx][oc] = fmaf(wv, reg[dy + ky][dx + kx], acc[dy][dx][oc]);
          }
      }
    }
  }
  const int py = py0 + ty, px = px0 + tx;
#pragma unroll
  for (int oc = 0; oc < 8; ++oc) {
    float bb = b[ocg * 8 + oc];
    float v00 = fmaxf(acc[0][0][oc] + bb, 0.f);
    float v01 = fmaxf(acc[0][1][oc] + bb, 0.f);
    float v10 = fmaxf(acc[1][0][oc] + bb, 0.f);
    float v11 = fmaxf(acc[1][1][oc] + bb, 0.f);
    pooled[(ocg * 8 + oc) * 65536 + py * 256 + px] = fmaxf(fmaxf(v00, v01), fmaxf(v10, v11));
  }
}

// -------- conv3: 64 -> 128, 3x3 pad1, relu, fused global mean (partials) ----
__global__ __launch_bounds__(256) void k_conv3mean(const float* __restrict__ pooled,
                                                   const float* __restrict__ w,
                                                   const float* __restrict__ b,
                                                   float* __restrict__ feat_part) {
  __shared__ float tile[8][18][18];
  __shared__ float red[32];
  const int tx = threadIdx.x & 15, ty = threadIdx.x >> 4;
  const int x0 = blockIdx.x * 16, y0 = blockIdx.y * 16;
  const int ocg = blockIdx.z;  // 8 output channels per block
  float acc[8];
#pragma unroll
  for (int o = 0; o < 8; ++o) acc[o] = 0.f;
  for (int icc = 0; icc < 8; ++icc) {
    __syncthreads();
    for (int idx = threadIdx.x; idx < 8 * 18 * 18; idx += 256) {
      int ic = idx / 324, r = idx - ic * 324;
      int yy = r / 18, xx = r - yy * 18;
      int gy = y0 + yy - 1, gx = x0 + xx - 1;
      float v = 0.f;
      if ((unsigned)gy < 256u && (unsigned)gx < 256u)
        v = pooled[(icc * 8 + ic) * 65536 + gy * 256 + gx];
      tile[ic][yy][xx] = v;
    }
    __syncthreads();
#pragma unroll
    for (int ic = 0; ic < 8; ++ic) {
      float reg[3][3];
#pragma unroll
      for (int r = 0; r < 3; ++r)
#pragma unroll
        for (int c = 0; c < 3; ++c) reg[r][c] = tile[ic][ty + r][tx + c];
#pragma unroll
      for (int oc = 0; oc < 8; ++oc) {
        const float* wp = w + (((ocg * 8 + oc) * 64 + icc * 8 + ic) * 9);
#pragma unroll
        for (int ky = 0; ky < 3; ++ky)
#pragma unroll
          for (int kx = 0; kx < 3; ++kx)
            acc[oc] = fmaf(wp[ky * 3 + kx], reg[ky][kx], acc[oc]);
      }
    }
  }
  const int lane = threadIdx.x & 63, wid = threadIdx.x >> 6;
#pragma unroll
  for (int oc = 0; oc < 8; ++oc) {
    float v = fmaxf(acc[oc] + b[ocg * 8 + oc], 0.f);
    v = wave_reduce_sum(v);
    if (lane == 0) red[wid * 8 + oc] = v;
  }
  __syncthreads();
  if (threadIdx.x < 8) {
    float s = red[threadIdx.x] + red[8 + threadIdx.x] + red[16 + threadIdx.x] + red[24 + threadIdx.x];
    int bucket = (blockIdx.y * 16 + blockIdx.x) & 31;
    atomicAdd(&feat_part[bucket * 128 + ocg * 8 + (int)threadIdx.x], s);
  }
}

__global__ void k_featreduce(const float* __restrict__ feat_part, float* __restrict__ feat) {
  int j = threadIdx.x;  // 128 threads
  float s = 0.f;
  for (int bkt = 0; bkt < 32; ++bkt) s += feat_part[bkt * 128 + j];
  feat[j] = s * (1.f / 65536.f);
}

// ---------------- generic small matvec: y = relu(W x + b), wave per row ------
__global__ __launch_bounds__(256) void k_matvec_small(const float* __restrict__ W,
                                                      const float* __restrict__ b,
                                                      const float* __restrict__ x,
                                                      float* __restrict__ y,
                                                      int nrows, int ncols) {
  const int wid = threadIdx.x >> 6, lane = threadIdx.x & 63;
  const int row = blockIdx.x * 4 + wid;
  if (row >= nrows) return;
  const float* wr = W + (size_t)row * ncols;
  float p = 0.f;
  for (int c = lane; c < ncols; c += 64) p = fmaf(wr[c], x[c], p);
  p = wave_reduce_sum(p);
  if (lane == 0) y[row] = fmaxf(p + b[row], 0.f);
}

// ------- big head matvecs: u (131072x512), v (131072x512), s2 (128x256) -----
__global__ __launch_bounds__(256) void k_heads_big(
    const float* __restrict__ uw2, const float* __restrict__ ub2,
    const float* __restrict__ vw2, const float* __restrict__ vb2,
    const float* __restrict__ sw2, const float* __restrict__ sb2,
    const float* __restrict__ u1, const float* __restrict__ v1,
    const float* __restrict__ s1, float* __restrict__ u_buf,
    float* __restrict__ v_buf, float* __restrict__ s_raw) {
  const int wid = threadIdx.x >> 6, lane = threadIdx.x & 63;
  const int row = blockIdx.x * 4 + wid;
  if (row < 262144) {
    int r = row & 131071;
    const float* W = (row < 131072) ? uw2 : vw2;
    const float* xv = (row < 131072) ? u1 : v1;
    const float4* wr = (const float4*)(W + (size_t)r * 512);
    const float4* xp = (const float4*)xv;
    float4 a0 = wr[lane], a1 = wr[lane + 64];
    float4 b0 = xp[lane], b1 = xp[lane + 64];
    float p = a0.x * b0.x;
    p = fmaf(a0.y, b0.y, p); p = fmaf(a0.z, b0.z, p); p = fmaf(a0.w, b0.w, p);
    p = fmaf(a1.x, b1.x, p); p = fmaf(a1.y, b1.y, p);
    p = fmaf(a1.z, b1.z, p); p = fmaf(a1.w, b1.w, p);
    p = wave_reduce_sum(p);
    if (lane == 0) {
      if (row < 131072) u_buf[r] = p + ub2[r];
      else v_buf[r] = p + vb2[r];
    }
  } else {
    int r = row - 262144;  // 0..127
    if (r < 128) {
      const float* wr = sw2 + (size_t)r * 256;
      float p = 0.f;
      for (int c = lane; c < 256; c += 64) p = fmaf(wr[c], s1[c], p);
      p = wave_reduce_sum(p);
      if (lane == 0) {
        float z = p + sb2[r];
        s_raw[r] = (z > 20.f) ? z : log1pf(expf(z));
      }
    }
  }
}

// ---------------- sort s descending (stable, matches sort+reverse) ----------
__global__ void k_sort(const float* __restrict__ s_raw, float* __restrict__ out) {
  __shared__ float sv[128];
  const int t = threadIdx.x;  // 128 threads
  float v = s_raw[t];
  sv[t] = v;
  __syncthreads();
  int rank = 0;
  for (int k = 0; k < 128; ++k) {
    float o = sv[k];
    rank += (o > v) || (o == v && k > t);
  }
  out[rank] = v;
}

// ----- G = X^H X (+eps I), upper triangle; strict lower zero-filled ---------
__global__ __launch_bounds__(256) void k_gram(const float* __restrict__ Xu,
                                              const float* __restrict__ Xv,
                                              float2* __restrict__ Gu,
                                              float2* __restrict__ Gv) {
  const int mat = blockIdx.z;
  const float* X = mat ? Xv : Xu;
  float2* G = mat ? Gv : Gu;
  const int bi = blockIdx.y, bj = blockIdx.x;
  const int ti = threadIdx.x >> 4, tj = threadIdx.x & 15;
  const int i = bi * 16 + ti, j = bj * 16 + tj;
  if (bi > bj) {  // uniform across block
    G[i * 128 + j] = make_float2(0.f, 0.f);
    return;
  }
  __shared__ float2 A[32][16];
  __shared__ float2 B[32][16];
  float are = 0.f, aim = 0.f;
  for (int m0 = 0; m0 < 512; m0 += 32) {
    __syncthreads();
    for (int t = threadIdx.x; t < 512; t += 256) {
      int ml = t >> 4, c = t & 15;
      A[ml][c] = *(const float2*)(X + (m0 + ml) * 256 + (bi * 16 + c) * 2);
      B[ml][c] = *(const float2*)(X + (m0 + ml) * 256 + (bj * 16 + c) * 2);
    }
    __syncthreads();
#pragma unroll
    for (int ml = 0; ml < 32; ++ml) {
      float2 a = A[ml][ti], bb = B[ml][tj];
      are = fmaf(a.x, bb.x, fmaf(a.y, bb.y, are));   // conj(a)*b real
      aim = fmaf(a.x, bb.y, fmaf(-a.y, bb.x, aim));  // conj(a)*b imag
    }
  }
  if (i > j) G[i * 128 + j] = make_float2(0.f, 0.f);
  else if (i == j) G[i * 128 + j] = make_float2(are + 1e-8f, 0.f);
  else G[i * 128 + j] = make_float2(are, aim);
}

// ------------- in-place Hermitian factorization (upper): G -> R, R^H R = G --
// Deferred-normalization right-looking: per column j (unscaled pivot row),
//   A[i][k] -= conj(A[j][i]) A[j][k] / D[j]   (i>j, k>i),  D[i] -= |A[j][i]|^2/D[j]
// One barrier per column. Final pass: R[j][k] = A[j][k]/sqrt(D[j]),
// R[j][j] = sqrt(D[j]). Identical to Cholesky in exact arithmetic.
// LDS: packed strict-upper triangle (8128 float2) + diag (128 f32) = 64 KiB.
__device__ __forceinline__ int rof(int i) { return (i * (255 - i)) >> 1; }
__device__ __forceinline__ int row_of(int idx) {
  int i = (int)(127.5f - sqrtf(16256.25f - 2.0f * (float)idx));
  if (i < 0) i = 0;
  if (i > 126) i = 126;
  while (rof(i + 1) <= idx) ++i;
  while (rof(i) > idx) --i;
  return i;
}

__global__ __launch_bounds__(1024) void k_chol(float2* __restrict__ Gu, float2* __restrict__ Gv) {
  float2* G = blockIdx.x ? Gv : Gu;
  __shared__ float smem[16384];  // 64 KiB exactly
  float2* U = (float2*)smem;     // [0..8128) packed strict-upper
  float* diag = smem + 16256;    // [16256..16384)
  const int tid = threadIdx.x;   // 1024 threads = 16 waves
  const int g = tid >> 6, lane = tid & 63;
  // ---- load from global ----
  for (int j = tid; j < 128; j += 1024) diag[j] = G[j * 128 + j].x;  // has +1e-8
  for (int idx = tid; idx < 8128; idx += 1024) {
    int i = row_of(idx);
    int k = i + 1 + (idx - rof(i));
    U[idx] = G[i * 128 + k];
  }
  // ---- deferred-normalization factorization: 1 barrier per column ----
  // Wave g owns rows i = j+1+g+16r (r=0..7); lane owns cols k0=j+1+lane,
  // k1=k0+64. All LDS reads batched before any write (no alias stalls).
  for (int j = 0; j < 127; ++j) {
    __syncthreads();
    const float invd = 1.f / diag[j];
    const int base_j = rof(j) - j - 1;
    const int k0 = j + 1 + lane;
    const int k1 = k0 + 64;
    const int k0c = (k0 < 127) ? k0 : 127;
    const int k1c = (k1 < 127) ? k1 : 127;
    // ---- read phase ----
    float2 rjk0 = U[base_j + k0c];
    float2 rjk1 = U[base_j + k1c];
    float2 rji[8], cur0[8], cur1[8];
#pragma unroll
    for (int r = 0; r < 8; ++r) {
      int i = j + 1 + g + 16 * r;
      int ic = (i < 127) ? i : 127;
      rji[r] = U[base_j + ic];  // wave-uniform -> broadcast
      int base_i = rof(ic) - ic - 1;
      cur0[r] = U[base_i + k0c];  // clamped reads in-range; unused lanes discard
      cur1[r] = U[base_i + k1c];
    }
    // ---- compute + write phase ----
#pragma unroll
    for (int r = 0; r < 8; ++r) {
      int i = j + 1 + g + 16 * r;
      int ic = (i < 127) ? i : 127;
      int base_i = rof(ic) - ic - 1;
      float are = rji[r].x, aim = rji[r].y;
      {
        float2 b = rjk0, c = cur0[r];
        c.x -= fmaf(are, b.x, aim * b.y) * invd;    // conj(a)*b real / d
        c.y -= fmaf(are, b.y, -aim * b.x) * invd;   // conj(a)*b imag / d
        if (i < 128 && k0 > i && k0 < 128) U[base_i + k0] = c;
        if (i < 128 && k0 == i) diag[i] -= fmaf(are, are, aim * aim) * invd;
      }
      {
        float2 b = rjk1, c = cur1[r];
        c.x -= fmaf(are, b.x, aim * b.y) * invd;
        c.y -= fmaf(are, b.y, -aim * b.x) * invd;
        if (i < 128 && k1 > i && k1 < 128) U[base_i + k1] = c;
        if (i < 128 && k1 == i) diag[i] -= fmaf(are, are, aim * aim) * invd;
      }
    }
  }
  __syncthreads();
  // ---- final normalization + store back (lower triangle already zero) ----
  for (int idx = tid; idx < 8128; idx += 1024) {
    int i = row_of(idx);
    float s = 1.f / sqrtf(diag[i]);
    int k = i + 1 + (idx - rof(i));
    float2 v = U[idx];
    v.x *= s; v.y *= s;
    G[i * 128 + k] = v;
  }
  for (int j = tid; j < 128; j += 1024) G[j * 128 + j] = make_float2(sqrtf(diag[j]), 0.f);
}

// --------- Q = X R^-1, wave-per-row forward substitution, write d_out -------
__global__ __launch_bounds__(256) void k_solve(const float* __restrict__ Xu,
                                               const float* __restrict__ Xv,
                                               const float2* __restrict__ Gu,
                                               const float2* __restrict__ Gv,
                                               float* __restrict__ out) {
  const int wid = threadIdx.x >> 6, lane = threadIdx.x & 63;
  const int gw = blockIdx.x * 4 + wid;  // 0..1023
  const int mat = gw >> 9, m = gw & 511;
  const float* X = mat ? Xv : Xu;
  const float* R = (const float*)(mat ? Gv : Gu);
  float* o = out + (mat ? 131200 : 0);
  float4 xv = *(const float4*)(X + m * 256 + lane * 4);  // cols 2l (x,y), 2l+1 (z,w)
  float S0re = 0.f, S0im = 0.f, S1re = 0.f, S1im = 0.f;
  float q0re = 0.f, q0im = 0.f, q1re = 0.f, q1im = 0.f;
  float4 rp = *(const float4*)(R + lane * 4);  // row 0
  for (int i = 0; i < 128; ++i) {
    float4 rp_next;
    if (i < 127) rp_next = *(const float4*)(R + (i + 1) * 256 + lane * 4);
    const bool odd = (i & 1);
    float d = odd ? rp.z : rp.x;  // true diagonal only in owner lane (i>>1)
    float xs_re = odd ? xv.z : xv.x, xs_im = odd ? xv.w : xv.y;
    float Ss_re = odd ? S1re : S0re, Ss_im = odd ? S1im : S0im;
    float invd = 1.f / d;  // garbage in non-owner lanes, discarded by shuffle
    float qre = (xs_re - Ss_re) * invd;
    float qim = (xs_im - Ss_im) * invd;
    qre = __shfl(qre, i >> 1, 64);
    qim = __shfl(qim, i >> 1, 64);
    if (lane == (i >> 1)) {
      if (odd) { q1re = qre; q1im = qim; }
      else     { q0re = qre; q0im = qim; }
    }
    // S_j += q_i * R[i][j]  (R lower triangle is zero -> harmless for j <= i)
    S0re = fmaf(qre, rp.x, fmaf(-qim, rp.y, S0re));
    S0im = fmaf(qre, rp.y, fmaf(qim, rp.x, S0im));
    S1re = fmaf(qre, rp.z, fmaf(-qim, rp.w, S1re));
    S1im = fmaf(qre, rp.w, fmaf(qim, rp.z, S1im));
    rp = rp_next;
  }
  *(float4*)(o + m * 256 + lane * 4) = make_float4(q0re, q0im, q1re, q1im);
}

// ---------------------------------------------------------------------------
extern "C" void kernel_launch(void* const* d_in, const int* in_sizes, int n_in,
                              void* d_out, int out_size, void* d_ws, size_t ws_size,
                              hipStream_t stream) {
  const float* x   = (const float*)d_in[0];
  const float* cw1 = (const float*)d_in[1];  const float* cb1 = (const float*)d_in[2];
  const float* cw2 = (const float*)d_in[3];  const float* cb2 = (const float*)d_in[4];
  const float* cw3 = (const float*)d_in[5];  const float* cb3 = (const float*)d_in[6];
  const float* fw1 = (const float*)d_in[7];  const float* fb1 = (const float*)d_in[8];
  const float* fw2 = (const float*)d_in[9];  const float* fb2 = (const float*)d_in[10];
  const float* sw1 = (const float*)d_in[11]; const float* sb1 = (const float*)d_in[12];
  const float* sw2 = (const float*)d_in[13]; const float* sb2 = (const float*)d_in[14];
  const float* uw1 = (const float*)d_in[15]; const float* ub1 = (const float*)d_in[16];
  const float* uw2 = (const float*)d_in[17]; const float* ub2 = (const float*)d_in[18];
  const float* vw1 = (const float*)d_in[19]; const float* vb1 = (const float*)d_in[20];
  const float* vw2 = (const float*)d_in[21]; const float* vb2 = (const float*)d_in[22];

  float* ws = (float*)d_ws;
  float* h1        = ws;                    // 8388608
  float* pooled    = h1 + 8388608;          // 4194304
  float* feat_part = pooled + 4194304;      // 4096
  float* feat      = feat_part + 4096;      // 128
  float* y1        = feat + 128;            // 256
  float* f         = y1 + 256;              // 512
  float* s1        = f + 512;               // 256
  float* u1        = s1 + 256;              // 512
  float* v1        = u1 + 512;              // 512
  float* s_raw     = v1 + 512;              // 128
  float* u_buf     = s_raw + 128;           // 131072
  float* v_buf     = u_buf + 131072;        // 131072
  float2* Gu       = (float2*)(v_buf + 131072);  // 16384 float2
  float2* Gv       = Gu + 16384;                 // 16384 float2

  float* outp = (float*)d_out;  // [Qu 131072 | s 128 | Qv 131072]

  k_zero<<<16, 256, 0, stream>>>(feat_part, 4096);
  k_conv1<<<dim3(32, 32), 256, 0, stream>>>(x, cw1, cb1, h1);
  k_conv2pool<<<dim3(16, 16, 8), 256, 0, stream>>>(h1, cw2, cb2, pooled);
  k_conv3mean<<<dim3(16, 16, 16), 256, 0, stream>>>(pooled, cw3, cb3, feat_part);
  k_featreduce<<<1, 128, 0, stream>>>(feat_part, feat);
  k_matvec_small<<<64, 256, 0, stream>>>(fw1, fb1, feat, y1, 256, 128);
  k_matvec_small<<<128, 256, 0, stream>>>(fw2, fb2, y1, f, 512, 256);
  k_matvec_small<<<64, 256, 0, stream>>>(sw1, sb1, f, s1, 256, 512);
  k_matvec_small<<<128, 256, 0, stream>>>(uw1, ub1, f, u1, 512, 512);
  k_matvec_small<<<128, 256, 0, stream>>>(vw1, vb1, f, v1, 512, 512);
  k_heads_big<<<65568, 256, 0, stream>>>(uw2, ub2, vw2, vb2, sw2, sb2,
                                         u1, v1, s1, u_buf, v_buf, s_raw);
  k_sort<<<1, 128, 0, stream>>>(s_raw, outp + 131072);
  k_gram<<<dim3(8, 8, 2), 256, 0, stream>>>(u_buf, v_buf, Gu, Gv);
  k_chol<<<2, 1024, 0, stream>>>(Gu, Gv);
  k_solve<<<256, 256, 0, stream>>>(u_buf, v_buf, Gu, Gv, outp);
}

// Round 3
// 1378.750 us; speedup vs baseline: 1.3166x; 1.0416x over previous
//
#include <hip/hip_runtime.h>
#include <math.h>

// ---------------------------------------------------------------------------
// SVDNet: conv stack -> fc trunk -> {s head + sort, u/v heads -> CholeskyQR}
// All fp32. CholeskyQR (G = X^H X + eps*I, G = R^H R, Q = X R^-1) replaces the
// reference's sequential modified Gram-Schmidt (identical in exact arithmetic).
// R2: k_chol LDS-resident (packed upper triangle, 64 KiB).
// R3: k_chol deferred-normalization (LDL-style), 1 barrier/col: 596 -> <50 us.
// R4: k_conv3mean restructured to 2x2 patch per thread (conv2's schedule):
//     16 LDS reads -> 288 FMAs per ic (was 9 reads -> 72 FMAs). LDS pipe was
//     over the VALU floor; now under it. Was 314 us, predicted ~100 us.
// ---------------------------------------------------------------------------

__device__ __forceinline__ float wave_reduce_sum(float v) {
#pragma unroll
  for (int off = 32; off > 0; off >>= 1) v += __shfl_down(v, off, 64);
  return v;
}

__global__ void k_zero(float* __restrict__ p, int n) {
  int i = blockIdx.x * 256 + threadIdx.x;
  if (i < n) p[i] = 0.f;
}

// ---------------- conv1: 2 -> 32, 3x3 pad1, relu, 512x512, CHW out ----------
__global__ __launch_bounds__(256) void k_conv1(const float* __restrict__ x,
                                               const float* __restrict__ w,
                                               const float* __restrict__ b,
                                               float* __restrict__ h1) {
  __shared__ float tile[2][18][18];
  const int tx = threadIdx.x & 15, ty = threadIdx.x >> 4;
  const int bx = blockIdx.x * 16, by = blockIdx.y * 16;
  for (int idx = threadIdx.x; idx < 2 * 18 * 18; idx += 256) {
    int c = idx / 324, r = idx - c * 324;
    int yy = r / 18, xx = r - yy * 18;
    int gy = by + yy - 1, gx = bx + xx - 1;
    float v = 0.f;
    if ((unsigned)gy < 512u && (unsigned)gx < 512u) v = x[(gy * 512 + gx) * 2 + c];
    tile[c][yy][xx] = v;
  }
  __syncthreads();
  float in[2][3][3];
#pragma unroll
  for (int c = 0; c < 2; ++c)
#pragma unroll
    for (int ky = 0; ky < 3; ++ky)
#pragma unroll
      for (int kx = 0; kx < 3; ++kx) in[c][ky][kx] = tile[c][ty + ky][tx + kx];
  const int gy = by + ty, gx = bx + tx;
#pragma unroll 4
  for (int oc = 0; oc < 32; ++oc) {
    float acc = b[oc];
#pragma unroll
    for (int c = 0; c < 2; ++c)
#pragma unroll
      for (int ky = 0; ky < 3; ++ky)
#pragma unroll
        for (int kx = 0; kx < 3; ++kx)
          acc = fmaf(w[((oc * 2 + c) * 3 + ky) * 3 + kx], in[c][ky][kx], acc);
    h1[oc * 262144 + gy * 512 + gx] = fmaxf(acc, 0.f);
  }
}

// -------- conv2: 32 -> 64, 3x3 pad1, relu, then 2x2 maxpool -> (64,256,256) --
__global__ __launch_bounds__(256) void k_conv2pool(const float* __restrict__ h1,
                                                   const float* __restrict__ w,
                                                   const float* __restrict__ b,
                                                   float* __restrict__ pooled) {
  __shared__ float tile[8][34][34];  // 37 KB
  const int tx = threadIdx.x & 15, ty = threadIdx.x >> 4;
  const int px0 = blockIdx.x * 16, py0 = blockIdx.y * 16;
  const int ocg = blockIdx.z;  // 8 output channels per block
  const int cx0 = px0 * 2 - 1, cy0 = py0 * 2 - 1;
  float acc[2][2][8];
#pragma unroll
  for (int a = 0; a < 2; ++a)
#pragma unroll
    for (int c = 0; c < 2; ++c)
#pragma unroll
      for (int o = 0; o < 8; ++o) acc[a][c][o] = 0.f;
  for (int icc = 0; icc < 4; ++icc) {
    __syncthreads();
    for (int idx = threadIdx.x; idx < 8 * 34 * 34; idx += 256) {
      int ic = idx / 1156, r = idx - ic * 1156;
      int yy = r / 34, xx = r - yy * 34;
      int gy = cy0 + yy, gx = cx0 + xx;
      float v = 0.f;
      if ((unsigned)gy < 512u && (unsigned)gx < 512u)
        v = h1[(icc * 8 + ic) * 262144 + gy * 512 + gx];
      tile[ic][yy][xx] = v;
    }
    __syncthreads();
#pragma unroll
    for (int ic = 0; ic < 8; ++ic) {
      float reg[4][4];
#pragma unroll
      for (int r = 0; r < 4; ++r)
#pragma unroll
        for (int c = 0; c < 4; ++c) reg[r][c] = tile[ic][2 * ty + r][2 * tx + c];
#pragma unroll
      for (int oc = 0; oc < 8; ++oc) {
        const float* wp = w + (((ocg * 8 + oc) * 32 + icc * 8 + ic) * 9);
#pragma unroll
        for (int ky = 0; ky < 3; ++ky)
#pragma unroll
          for (int kx = 0; kx < 3; ++kx) {
            float wv = wp[ky * 3 + kx];  // uniform -> scalar load
#pragma unroll
            for (int dy = 0; dy < 2; ++dy)
#pragma unroll
              for (int dx = 0; dx < 2; ++dx)
                acc[dy][dx][oc] = fmaf(wv, reg[dy + ky][dx + kx], acc[dy][dx][oc]);
          }
      }
    }
  }
  const int py = py0 + ty, px = px0 + tx;
#pragma unroll
  for (int oc = 0; oc < 8; ++oc) {
    float bb = b[ocg * 8 + oc];
    float v00 = fmaxf(acc[0][0][oc] + bb, 0.f);
    float v01 = fmaxf(acc[0][1][oc] + bb, 0.f);
    float v10 = fmaxf(acc[1][0][oc] + bb, 0.f);
    float v11 = fmaxf(acc[1][1][oc] + bb, 0.f);
    pooled[(ocg * 8 + oc) * 65536 + py * 256 + px] = fmaxf(fmaxf(v00, v01), fmaxf(v10, v11));
  }
}

// -------- conv3: 64 -> 128, 3x3 pad1, relu, fused global mean (partials) ----
// R4: 2x2 output patch per thread, 32x32 tile per block, 8 oc per block.
__global__ __launch_bounds__(256) void k_conv3mean(const float* __restrict__ pooled,
                                                   const float* __restrict__ w,
                                                   const float* __restrict__ b,
                                                   float* __restrict__ feat_part) {
  __shared__ float tile[8][34][34];  // 37 KB
  __shared__ float red[32];
  const int tx = threadIdx.x & 15, ty = threadIdx.x >> 4;
  const int x0 = blockIdx.x * 32, y0 = blockIdx.y * 32;
  const int ocg = blockIdx.z;  // 8 output channels per block
  float acc[2][2][8];
#pragma unroll
  for (int a = 0; a < 2; ++a)
#pragma unroll
    for (int c = 0; c < 2; ++c)
#pragma unroll
      for (int o = 0; o < 8; ++o) acc[a][c][o] = 0.f;
  for (int icc = 0; icc < 8; ++icc) {
    __syncthreads();
    for (int idx = threadIdx.x; idx < 8 * 34 * 34; idx += 256) {
      int ic = idx / 1156, r = idx - ic * 1156;
      int yy = r / 34, xx = r - yy * 34;
      int gy = y0 + yy - 1, gx = x0 + xx - 1;
      float v = 0.f;
      if ((unsigned)gy < 256u && (unsigned)gx < 256u)
        v = pooled[(icc * 8 + ic) * 65536 + gy * 256 + gx];
      tile[ic][yy][xx] = v;
    }
    __syncthreads();
#pragma unroll
    for (int ic = 0; ic < 8; ++ic) {
      float reg[4][4];
#pragma unroll
      for (int r = 0; r < 4; ++r)
#pragma unroll
        for (int c = 0; c < 4; ++c) reg[r][c] = tile[ic][2 * ty + r][2 * tx + c];
#pragma unroll
      for (int oc = 0; oc < 8; ++oc) {
        const float* wp = w + (((ocg * 8 + oc) * 64 + icc * 8 + ic) * 9);
#pragma unroll
        for (int ky = 0; ky < 3; ++ky)
#pragma unroll
          for (int kx = 0; kx < 3; ++kx) {
            float wv = wp[ky * 3 + kx];  // uniform -> scalar load
#pragma unroll
            for (int dy = 0; dy < 2; ++dy)
#pragma unroll
              for (int dx = 0; dx < 2; ++dx)
                acc[dy][dx][oc] = fmaf(wv, reg[dy + ky][dx + kx], acc[dy][dx][oc]);
          }
      }
    }
  }
  const int lane = threadIdx.x & 63, wid = threadIdx.x >> 6;
#pragma unroll
  for (int oc = 0; oc < 8; ++oc) {
    float bb = b[ocg * 8 + oc];
    float v = fmaxf(acc[0][0][oc] + bb, 0.f) + fmaxf(acc[0][1][oc] + bb, 0.f) +
              fmaxf(acc[1][0][oc] + bb, 0.f) + fmaxf(acc[1][1][oc] + bb, 0.f);
    v = wave_reduce_sum(v);
    if (lane == 0) red[wid * 8 + oc] = v;
  }
  __syncthreads();
  if (threadIdx.x < 8) {
    float s = red[threadIdx.x] + red[8 + threadIdx.x] + red[16 + threadIdx.x] + red[24 + threadIdx.x];
    int bucket = (blockIdx.y * 8 + blockIdx.x) & 31;
    atomicAdd(&feat_part[bucket * 128 + ocg * 8 + (int)threadIdx.x], s);
  }
}

__global__ void k_featreduce(const float* __restrict__ feat_part, float* __restrict__ feat) {
  int j = threadIdx.x;  // 128 threads
  float s = 0.f;
  for (int bkt = 0; bkt < 32; ++bkt) s += feat_part[bkt * 128 + j];
  feat[j] = s * (1.f / 65536.f);
}

// ---------------- generic small matvec: y = relu(W x + b), wave per row ------
__global__ __launch_bounds__(256) void k_matvec_small(const float* __restrict__ W,
                                                      const float* __restrict__ b,
                                                      const float* __restrict__ x,
                                                      float* __restrict__ y,
                                                      int nrows, int ncols) {
  const int wid = threadIdx.x >> 6, lane = threadIdx.x & 63;
  const int row = blockIdx.x * 4 + wid;
  if (row >= nrows) return;
  const float* wr = W + (size_t)row * ncols;
  float p = 0.f;
  for (int c = lane; c < ncols; c += 64) p = fmaf(wr[c], x[c], p);
  p = wave_reduce_sum(p);
  if (lane == 0) y[row] = fmaxf(p + b[row], 0.f);
}

// ------- big head matvecs: u (131072x512), v (131072x512), s2 (128x256) -----
__global__ __launch_bounds__(256) void k_heads_big(
    const float* __restrict__ uw2, const float* __restrict__ ub2,
    const float* __restrict__ vw2, const float* __restrict__ vb2,
    const float* __restrict__ sw2, const float* __restrict__ sb2,
    const float* __restrict__ u1, const float* __restrict__ v1,
    const float* __restrict__ s1, float* __restrict__ u_buf,
    float* __restrict__ v_buf, float* __restrict__ s_raw) {
  const int wid = threadIdx.x >> 6, lane = threadIdx.x & 63;
  const int row = blockIdx.x * 4 + wid;
  if (row < 262144) {
    int r = row & 131071;
    const float* W = (row < 131072) ? uw2 : vw2;
    const float* xv = (row < 131072) ? u1 : v1;
    const float4* wr = (const float4*)(W + (size_t)r * 512);
    const float4* xp = (const float4*)xv;
    float4 a0 = wr[lane], a1 = wr[lane + 64];
    float4 b0 = xp[lane], b1 = xp[lane + 64];
    float p = a0.x * b0.x;
    p = fmaf(a0.y, b0.y, p); p = fmaf(a0.z, b0.z, p); p = fmaf(a0.w, b0.w, p);
    p = fmaf(a1.x, b1.x, p); p = fmaf(a1.y, b1.y, p);
    p = fmaf(a1.z, b1.z, p); p = fmaf(a1.w, b1.w, p);
    p = wave_reduce_sum(p);
    if (lane == 0) {
      if (row < 131072) u_buf[r] = p + ub2[r];
      else v_buf[r] = p + vb2[r];
    }
  } else {
    int r = row - 262144;  // 0..127
    if (r < 128) {
      const float* wr = sw2 + (size_t)r * 256;
      float p = 0.f;
      for (int c = lane; c < 256; c += 64) p = fmaf(wr[c], s1[c], p);
      p = wave_reduce_sum(p);
      if (lane == 0) {
        float z = p + sb2[r];
        s_raw[r] = (z > 20.f) ? z : log1pf(expf(z));
      }
    }
  }
}

// ---------------- sort s descending (stable, matches sort+reverse) ----------
__global__ void k_sort(const float* __restrict__ s_raw, float* __restrict__ out) {
  __shared__ float sv[128];
  const int t = threadIdx.x;  // 128 threads
  float v = s_raw[t];
  sv[t] = v;
  __syncthreads();
  int rank = 0;
  for (int k = 0; k < 128; ++k) {
    float o = sv[k];
    rank += (o > v) || (o == v && k > t);
  }
  out[rank] = v;
}

// ----- G = X^H X (+eps I), upper triangle; strict lower zero-filled ---------
__global__ __launch_bounds__(256) void k_gram(const float* __restrict__ Xu,
                                              const float* __restrict__ Xv,
                                              float2* __restrict__ Gu,
                                              float2* __restrict__ Gv) {
  const int mat = blockIdx.z;
  const float* X = mat ? Xv : Xu;
  float2* G = mat ? Gv : Gu;
  const int bi = blockIdx.y, bj = blockIdx.x;
  const int ti = threadIdx.x >> 4, tj = threadIdx.x & 15;
  const int i = bi * 16 + ti, j = bj * 16 + tj;
  if (bi > bj) {  // uniform across block
    G[i * 128 + j] = make_float2(0.f, 0.f);
    return;
  }
  __shared__ float2 A[32][16];
  __shared__ float2 B[32][16];
  float are = 0.f, aim = 0.f;
  for (int m0 = 0; m0 < 512; m0 += 32) {
    __syncthreads();
    for (int t = threadIdx.x; t < 512; t += 256) {
      int ml = t >> 4, c = t & 15;
      A[ml][c] = *(const float2*)(X + (m0 + ml) * 256 + (bi * 16 + c) * 2);
      B[ml][c] = *(const float2*)(X + (m0 + ml) * 256 + (bj * 16 + c) * 2);
    }
    __syncthreads();
#pragma unroll
    for (int ml = 0; ml < 32; ++ml) {
      float2 a = A[ml][ti], bb = B[ml][tj];
      are = fmaf(a.x, bb.x, fmaf(a.y, bb.y, are));   // conj(a)*b real
      aim = fmaf(a.x, bb.y, fmaf(-a.y, bb.x, aim));  // conj(a)*b imag
    }
  }
  if (i > j) G[i * 128 + j] = make_float2(0.f, 0.f);
  else if (i == j) G[i * 128 + j] = make_float2(are + 1e-8f, 0.f);
  else G[i * 128 + j] = make_float2(are, aim);
}

// ------------- in-place Hermitian factorization (upper): G -> R, R^H R = G --
// Deferred-normalization right-looking: per column j (unscaled pivot row),
//   A[i][k] -= conj(A[j][i]) A[j][k] / D[j]   (i>j, k>i),  D[i] -= |A[j][i]|^2/D[j]
// One barrier per column. Final pass: R[j][k] = A[j][k]/sqrt(D[j]),
// R[j][j] = sqrt(D[j]). Identical to Cholesky in exact arithmetic.
// LDS: packed strict-upper triangle (8128 float2) + diag (128 f32) = 64 KiB.
__device__ __forceinline__ int rof(int i) { return (i * (255 - i)) >> 1; }
__device__ __forceinline__ int row_of(int idx) {
  int i = (int)(127.5f - sqrtf(16256.25f - 2.0f * (float)idx));
  if (i < 0) i = 0;
  if (i > 126) i = 126;
  while (rof(i + 1) <= idx) ++i;
  while (rof(i) > idx) --i;
  return i;
}

__global__ __launch_bounds__(1024) void k_chol(float2* __restrict__ Gu, float2* __restrict__ Gv) {
  float2* G = blockIdx.x ? Gv : Gu;
  __shared__ float smem[16384];  // 64 KiB exactly
  float2* U = (float2*)smem;     // [0..8128) packed strict-upper
  float* diag = smem + 16256;    // [16256..16384)
  const int tid = threadIdx.x;   // 1024 threads = 16 waves
  const int g = tid >> 6, lane = tid & 63;
  // ---- load from global ----
  for (int j = tid; j < 128; j += 1024) diag[j] = G[j * 128 + j].x;  // has +1e-8
  for (int idx = tid; idx < 8128; idx += 1024) {
    int i = row_of(idx);
    int k = i + 1 + (idx - rof(i));
    U[idx] = G[i * 128 + k];
  }
  // ---- deferred-normalization factorization: 1 barrier per column ----
  for (int j = 0; j < 127; ++j) {
    __syncthreads();
    const float invd = 1.f / diag[j];
    const int base_j = rof(j) - j - 1;
    const int k0 = j + 1 + lane;
    const int k1 = k0 + 64;
    const int k0c = (k0 < 127) ? k0 : 127;
    const int k1c = (k1 < 127) ? k1 : 127;
    // ---- read phase ----
    float2 rjk0 = U[base_j + k0c];
    float2 rjk1 = U[base_j + k1c];
    float2 rji[8], cur0[8], cur1[8];
#pragma unroll
    for (int r = 0; r < 8; ++r) {
      int i = j + 1 + g + 16 * r;
      int ic = (i < 127) ? i : 127;
      rji[r] = U[base_j + ic];  // wave-uniform -> broadcast
      int base_i = rof(ic) - ic - 1;
      cur0[r] = U[base_i + k0c];
      cur1[r] = U[base_i + k1c];
    }
    // ---- compute + write phase ----
#pragma unroll
    for (int r = 0; r < 8; ++r) {
      int i = j + 1 + g + 16 * r;
      int ic = (i < 127) ? i : 127;
      int base_i = rof(ic) - ic - 1;
      float are = rji[r].x, aim = rji[r].y;
      {
        float2 b = rjk0, c = cur0[r];
        c.x -= fmaf(are, b.x, aim * b.y) * invd;
        c.y -= fmaf(are, b.y, -aim * b.x) * invd;
        if (i < 128 && k0 > i && k0 < 128) U[base_i + k0] = c;
        if (i < 128 && k0 == i) diag[i] -= fmaf(are, are, aim * aim) * invd;
      }
      {
        float2 b = rjk1, c = cur1[r];
        c.x -= fmaf(are, b.x, aim * b.y) * invd;
        c.y -= fmaf(are, b.y, -aim * b.x) * invd;
        if (i < 128 && k1 > i && k1 < 128) U[base_i + k1] = c;
        if (i < 128 && k1 == i) diag[i] -= fmaf(are, are, aim * aim) * invd;
      }
    }
  }
  __syncthreads();
  // ---- final normalization + store back (lower triangle already zero) ----
  for (int idx = tid; idx < 8128; idx += 1024) {
    int i = row_of(idx);
    float s = 1.f / sqrtf(diag[i]);
    int k = i + 1 + (idx - rof(i));
    float2 v = U[idx];
    v.x *= s; v.y *= s;
    G[i * 128 + k] = v;
  }
  for (int j = tid; j < 128; j += 1024) G[j * 128 + j] = make_float2(sqrtf(diag[j]), 0.f);
}

// --------- Q = X R^-1, wave-per-row forward substitution, write d_out -------
__global__ __launch_bounds__(256) void k_solve(const float* __restrict__ Xu,
                                               const float* __restrict__ Xv,
                                               const float2* __restrict__ Gu,
                                               const float2* __restrict__ Gv,
                                               float* __restrict__ out) {
  const int wid = threadIdx.x >> 6, lane = threadIdx.x & 63;
  const int gw = blockIdx.x * 4 + wid;  // 0..1023
  const int mat = gw >> 9, m = gw & 511;
  const float* X = mat ? Xv : Xu;
  const float* R = (const float*)(mat ? Gv : Gu);
  float* o = out + (mat ? 131200 : 0);
  float4 xv = *(const float4*)(X + m * 256 + lane * 4);  // cols 2l (x,y), 2l+1 (z,w)
  float S0re = 0.f, S0im = 0.f, S1re = 0.f, S1im = 0.f;
  float q0re = 0.f, q0im = 0.f, q1re = 0.f, q1im = 0.f;
  float4 rp = *(const float4*)(R + lane * 4);  // row 0
  for (int i = 0; i < 128; ++i) {
    float4 rp_next;
    if (i < 127) rp_next = *(const float4*)(R + (i + 1) * 256 + lane * 4);
    const bool odd = (i & 1);
    float d = odd ? rp.z : rp.x;  // true diagonal only in owner lane (i>>1)
    float xs_re = odd ? xv.z : xv.x, xs_im = odd ? xv.w : xv.y;
    float Ss_re = odd ? S1re : S0re, Ss_im = odd ? S1im : S0im;
    float invd = 1.f / d;  // garbage in non-owner lanes, discarded by shuffle
    float qre = (xs_re - Ss_re) * invd;
    float qim = (xs_im - Ss_im) * invd;
    qre = __shfl(qre, i >> 1, 64);
    qim = __shfl(qim, i >> 1, 64);
    if (lane == (i >> 1)) {
      if (odd) { q1re = qre; q1im = qim; }
      else     { q0re = qre; q0im = qim; }
    }
    // S_j += q_i * R[i][j]  (R lower triangle is zero -> harmless for j <= i)
    S0re = fmaf(qre, rp.x, fmaf(-qim, rp.y, S0re));
    S0im = fmaf(qre, rp.y, fmaf(qim, rp.x, S0im));
    S1re = fmaf(qre, rp.z, fmaf(-qim, rp.w, S1re));
    S1im = fmaf(qre, rp.w, fmaf(qim, rp.z, S1im));
    rp = rp_next;
  }
  *(float4*)(o + m * 256 + lane * 4) = make_float4(q0re, q0im, q1re, q1im);
}

// ---------------------------------------------------------------------------
extern "C" void kernel_launch(void* const* d_in, const int* in_sizes, int n_in,
                              void* d_out, int out_size, void* d_ws, size_t ws_size,
                              hipStream_t stream) {
  const float* x   = (const float*)d_in[0];
  const float* cw1 = (const float*)d_in[1];  const float* cb1 = (const float*)d_in[2];
  const float* cw2 = (const float*)d_in[3];  const float* cb2 = (const float*)d_in[4];
  const float* cw3 = (const float*)d_in[5];  const float* cb3 = (const float*)d_in[6];
  const float* fw1 = (const float*)d_in[7];  const float* fb1 = (const float*)d_in[8];
  const float* fw2 = (const float*)d_in[9];  const float* fb2 = (const float*)d_in[10];
  const float* sw1 = (const float*)d_in[11]; const float* sb1 = (const float*)d_in[12];
  const float* sw2 = (const float*)d_in[13]; const float* sb2 = (const float*)d_in[14];
  const float* uw1 = (const float*)d_in[15]; const float* ub1 = (const float*)d_in[16];
  const float* uw2 = (const float*)d_in[17]; const float* ub2 = (const float*)d_in[18];
  const float* vw1 = (const float*)d_in[19]; const float* vb1 = (const float*)d_in[20];
  const float* vw2 = (const float*)d_in[21]; const float* vb2 = (const float*)d_in[22];

  float* ws = (float*)d_ws;
  float* h1        = ws;                    // 8388608
  float* pooled    = h1 + 8388608;          // 4194304
  float* feat_part = pooled + 4194304;      // 4096
  float* feat      = feat_part + 4096;      // 128
  float* y1        = feat + 128;            // 256
  float* f         = y1 + 256;              // 512
  float* s1        = f + 512;               // 256
  float* u1        = s1 + 256;              // 512
  float* v1        = u1 + 512;              // 512
  float* s_raw     = v1 + 512;              // 128
  float* u_buf     = s_raw + 128;           // 131072
  float* v_buf     = u_buf + 131072;        // 131072
  float2* Gu       = (float2*)(v_buf + 131072);  // 16384 float2
  float2* Gv       = Gu + 16384;                 // 16384 float2

  float* outp = (float*)d_out;  // [Qu 131072 | s 128 | Qv 131072]

  k_zero<<<16, 256, 0, stream>>>(feat_part, 4096);
  k_conv1<<<dim3(32, 32), 256, 0, stream>>>(x, cw1, cb1, h1);
  k_conv2pool<<<dim3(16, 16, 8), 256, 0, stream>>>(h1, cw2, cb2, pooled);
  k_conv3mean<<<dim3(8, 8, 16), 256, 0, stream>>>(pooled, cw3, cb3, feat_part);
  k_featreduce<<<1, 128, 0, stream>>>(feat_part, feat);
  k_matvec_small<<<64, 256, 0, stream>>>(fw1, fb1, feat, y1, 256, 128);
  k_matvec_small<<<128, 256, 0, stream>>>(fw2, fb2, y1, f, 512, 256);
  k_matvec_small<<<64, 256, 0, stream>>>(sw1, sb1, f, s1, 256, 512);
  k_matvec_small<<<128, 256, 0, stream>>>(uw1, ub1, f, u1, 512, 512);
  k_matvec_small<<<128, 256, 0, stream>>>(vw1, vb1, f, v1, 512, 512);
  k_heads_big<<<65568, 256, 0, stream>>>(uw2, ub2, vw2, vb2, sw2, sb2,
                                         u1, v1, s1, u_buf, v_buf, s_raw);
  k_sort<<<1, 128, 0, stream>>>(s_raw, outp + 131072);
  k_gram<<<dim3(8, 8, 2), 256, 0, stream>>>(u_buf, v_buf, Gu, Gv);
  k_chol<<<2, 1024, 0, stream>>>(Gu, Gv);
  k_solve<<<256, 256, 0, stream>>>(u_buf, v_buf, Gu, Gv, outp);
}